// Round 12
// baseline (687.820 us; speedup 1.0000x reference)
//
#include <hip/hip_runtime.h>
#include <hip/hip_bf16.h>

// Round 12: spatial-grid kNN (16^3 cells, w=0.5, expanding Chebyshev rings,
// exact per-cell min-dist culling, certified termination). Distance math and
// top-16 selection bit-identical to R11 (same FMA chain on same stored values;
// selection is order-independent over a certified superset). Pipeline
// otherwise identical to R11.

#define EPS 1e-5f

constexpr int Bb   = 8;
constexpr int Np   = 8192;
constexpr int Mq   = 2048;
constexpr int COUT = 128;
constexpr int BM   = Bb * Mq;        // 16384
constexpr int BMK  = BM * 16;        // 262144
constexpr int GC   = 16;             // grid cells per axis
constexpr int NC   = GC * GC * GC;   // 4096 cells

typedef __attribute__((ext_vector_type(8))) short short8;
typedef __attribute__((ext_vector_type(4))) float f32x4;

__device__ __forceinline__ unsigned short f2bf(float x) {
  unsigned u = __float_as_uint(x);
  u += 0x7fffu + ((u >> 16) & 1u);
  return (unsigned short)(u >> 16);
}
__device__ __forceinline__ float bf2f_lo(unsigned v) { return __uint_as_float(v << 16); }
__device__ __forceinline__ float bf2f_hi(unsigned v) { return __uint_as_float(v & 0xffff0000u); }

__device__ __forceinline__ int cell_of(float c) {
  int v = (int)floorf(c * 2.0f + 8.0f);
  return v < 0 ? 0 : (v > 15 ? 15 : v);
}

// stats float offsets: s1(9)@0, s2(64)@16, spt1(512)@128, spt2(512)@640, spout(256)@1152

__device__ __forceinline__ void bn1_compute(int o, const float* __restrict__ st,
                                            const float* __restrict__ W1,
                                            const float* __restrict__ b1,
                                            const float* __restrict__ g1,
                                            const float* __restrict__ be1,
                                            float* sc_out, float* shf_out) {
  float n = (float)BMK;
  float w0 = W1[3 * o], w1 = W1[3 * o + 1], w2 = W1[3 * o + 2], b = b1[o];
  float s0 = st[0], s1 = st[1], s2 = st[2];
  float m00 = st[3], m11 = st[4], m22 = st[5], m01 = st[6], m02 = st[7], m12 = st[8];
  float ws = (w0 * s0 + w1 * s1 + w2 * s2) / n;
  float mean = b + ws;
  float quad = w0 * w0 * m00 + w1 * w1 * m11 + w2 * w2 * m22 +
               2.f * (w0 * w1 * m01 + w0 * w2 * m02 + w1 * w2 * m12);
  float ex2 = quad / n + 2.f * b * ws + b * b;
  float var = ex2 - mean * mean;
  float sc = g1[o] * rsqrtf(var + EPS);
  *sc_out = sc;
  *shf_out = be1[o] - mean * sc + b * sc;
}

// ---------------- fused prep: pack pts (+cell histogram) | transpose x | Wc repack
__global__ __launch_bounds__(256) void prep_kernel(const float* __restrict__ p,
                                                   const float* __restrict__ x,
                                                   const float* __restrict__ Wc,
                                                   float4* __restrict__ pp4,
                                                   float* __restrict__ xt,
                                                   unsigned short* __restrict__ wcrp,
                                                   int* __restrict__ hist) {
  __shared__ float tile[64][65];
  int blk = blockIdx.x;
  int tid = threadIdx.x;
  if (blk < 256) {
    int i = blk * 256 + tid;  // < 65536
    float px = p[3 * i], py = p[3 * i + 1], pz = p[3 * i + 2];
    float pp = __fadd_rn(__fadd_rn(__fmul_rn(px, px), __fmul_rn(py, py)), __fmul_rn(pz, pz));
    pp4[i] = make_float4(px, py, pz, pp);
    int b = i >> 13;
    int cid = (cell_of(px) << 8) | (cell_of(py) << 4) | cell_of(pz);
    atomicAdd(&hist[b * NC + cid], 1);
  } else if (blk < 1280) {
    int bx = blk - 256;
    int b = bx >> 7;
    int n0 = (bx & 127) << 6;
    int nl = tid & 63;
    int r0 = tid >> 6;
    const float* xb = x + (size_t)b * 64 * Np;
    for (int c = r0; c < 64; c += 4) tile[c][nl] = xb[(size_t)c * Np + n0 + nl];
    __syncthreads();
    float* xtb = xt + (size_t)b * Np * 64;
    for (int n = r0; n < 64; n += 4) xtb[(size_t)(n0 + n) * 64 + nl] = tile[nl][n];
  } else {
    int g = (blk - 1280) * 256 + tid;
    if (g < 128 * 1536) {
      int o = g / 1536, r = g % 1536;
      int c = r % 96, j = r / 96;
      wcrp[g] = f2bf(Wc[(size_t)o * 1536 + c * 16 + j]);
    }
  }
}

// ---------------- exclusive prefix over 4096 cells per batch (1 block per batch)
__global__ __launch_bounds__(256) void prefix_kernel(const int* __restrict__ hist,
                                                     int* __restrict__ cellstart,
                                                     int* __restrict__ cursor) {
  __shared__ int ls[256];
  int b = blockIdx.x, t = threadIdx.x;
  const int* h = hist + b * NC;
  int loc[16], s = 0;
#pragma unroll
  for (int k = 0; k < 16; ++k) { loc[k] = h[t * 16 + k]; s += loc[k]; }
  ls[t] = s;
  __syncthreads();
  for (int off = 1; off < 256; off <<= 1) {
    int v = (t >= off) ? ls[t - off] : 0;
    __syncthreads();
    ls[t] += v;
    __syncthreads();
  }
  int run = ls[t] - s;
  int* cs = cellstart + b * (NC + 1);
  int* cu = cursor + b * NC;
#pragma unroll
  for (int k = 0; k < 16; ++k) {
    cs[t * 16 + k] = run;
    cu[t * 16 + k] = run;
    run += loc[k];
  }
  if (t == 255) cs[NC] = run;
}

// ---------------- scatter points into cell-sorted arrays
__global__ __launch_bounds__(256) void scatter_kernel(const float4* __restrict__ pp4,
                                                      int* __restrict__ cursor,
                                                      float4* __restrict__ sp4,
                                                      int* __restrict__ sidx) {
  int i = blockIdx.x * 256 + threadIdx.x;  // < 65536
  int b = i >> 13;
  float4 pv = pp4[i];
  int cid = (cell_of(pv.x) << 8) | (cell_of(pv.y) << 4) | cell_of(pv.z);
  int pos = atomicAdd(&cursor[b * NC + cid], 1);
  sp4[(size_t)b * Np + pos] = pv;
  sidx[(size_t)b * Np + pos] = i & 8191;
}

// ---------------- grid kNN: 1 query/wave, expanding Chebyshev rings.
__global__ __launch_bounds__(256) void knn_kernel(const float4* __restrict__ sp4,
                                                  const int* __restrict__ sidx,
                                                  const int* __restrict__ cellstart,
                                                  const float* __restrict__ q,
                                                  int* __restrict__ idx_out) {
  int tid = threadIdx.x;
  int wave = blockIdx.x * 4 + (tid >> 6);  // 0..16383
  int lane = tid & 63;
  int b = wave >> 11;
  const float4* sp = sp4 + (size_t)b * Np;
  const int* si = sidx + (size_t)b * Np;
  const int* cs = cellstart + b * (NC + 1);
  const float* qp = q + (size_t)wave * 3;
  float qx = qp[0], qy = qp[1], qz = qp[2];
  float qq = __fadd_rn(__fadd_rn(__fmul_rn(qx, qx), __fmul_rn(qy, qy)), __fmul_rn(qz, qz));
  unsigned long long key = ~0ULL;
  float tau_f = INFINITY;
  int cx = cell_of(qx), cy = cell_of(qy), cz = cell_of(qz);
  for (int r = 0; r < GC; ++r) {
    if (r >= 1) {
      float rb = 0.5f * (float)(r - 1);
      if (rb * rb * 0.9999f - 1e-5f > tau_f) break;  // all unvisited rings certified far
    }
    int ilo = max(0, cx - r), ihi = min(15, cx + r);
    int jlo = max(0, cy - r), jhi = min(15, cy + r);
    int klo = max(0, cz - r), khi = min(15, cz + r);
    for (int i = ilo; i <= ihi; ++i)
      for (int j = jlo; j <= jhi; ++j)
        for (int k = klo; k <= khi; ++k) {
          int ad = abs(i - cx), bd = abs(j - cy), cd = abs(k - cz);
          int mx = ad > bd ? ad : bd; mx = mx > cd ? mx : cd;
          if (mx != r) continue;
          // exact min-dist^2 to cell (edge cells extend to +-inf on outer side)
          float lox = -4.f + 0.5f * i, hix = lox + 0.5f;
          float loy = -4.f + 0.5f * j, hiy = loy + 0.5f;
          float loz = -4.f + 0.5f * k, hiz = loz + 0.5f;
          float dx = 0.f, dy = 0.f, dz = 0.f;
          if (i > 0 && qx < lox) dx = lox - qx; else if (i < 15 && qx > hix) dx = qx - hix;
          if (j > 0 && qy < loy) dy = loy - qy; else if (j < 15 && qy > hiy) dy = qy - hiy;
          if (k > 0 && qz < loz) dz = loz - qz; else if (k < 15 && qz > hiz) dz = qz - hiz;
          float mind2 = dx * dx + dy * dy + dz * dz;
          if (mind2 * 0.9999f - 1e-5f > tau_f) continue;
          int cid = (i << 8) | (j << 4) | k;
          int s0 = cs[cid], cnt = cs[cid + 1] - s0;
          for (int off = 0; off < cnt; off += 64) {
            int rel = off + lane;
            bool valid = rel < cnt;
            int li = s0 + (valid ? rel : 0);
            float4 pv = sp[li];
            int oidx = si[li];
            // BLAS-style K=3 FMA chain (identical to brute-force version):
            float e = __fmaf_rn(qz, pv.z, __fmaf_rn(qy, pv.y, __fmul_rn(qx, pv.x)));
            float d = __fadd_rn(__fsub_rn(qq, __fmul_rn(2.0f, e)), pv.w);
            if (!valid) d = __uint_as_float(0x7FC00000u);  // NaN: fails d<=tau always
            unsigned long long mask = __ballot(d <= tau_f);
            if (mask) {
              unsigned uu = __float_as_uint(d);
              uu ^= ((unsigned)(((int)uu) >> 31)) | 0x80000000u;  // monotone map
              unsigned long long cand = (((unsigned long long)uu) << 32) | (unsigned)oidx;
              do {
                int src = __ffsll((unsigned long long)mask) - 1;
                mask &= mask - 1;
                unsigned long long ck = __shfl(cand, src);
                unsigned long long up = __shfl_up(key, 1);
                if (lane == 0) up = 0ULL;
                if (lane < 16 && ck < key) key = (up > ck) ? up : ck;
              } while (mask);
              unsigned long long tau = __shfl(key, 15);
              unsigned tau_m = (unsigned)(tau >> 32);
              unsigned inv = tau_m ^ ((tau_m & 0x80000000u) ? 0x80000000u : 0xFFFFFFFFu);
              tau_f = (tau_m == 0xFFFFFFFFu) ? INFINITY : __uint_as_float(inv);
            }
          }
        }
  }
  if (lane < 16) idx_out[(size_t)wave * 16 + lane] = (int)(key & 0xffffffffULL);
}

// ---------------- gather phat + accumulate 9 phat moments
__global__ __launch_bounds__(256) void phat_stats_kernel(const float4* __restrict__ pp4,
                                                         const float* __restrict__ q,
                                                         const int* __restrict__ idx,
                                                         float* __restrict__ phat,
                                                         float* __restrict__ stats) {
  float a[9];
#pragma unroll
  for (int k = 0; k < 9; ++k) a[k] = 0.f;
  int tid = threadIdx.x;
  for (int it = 0; it < 4; ++it) {
    int bmk = blockIdx.x * 256 + tid + it * 65536;
    int bm = bmk >> 4;
    int b = bm >> 11;
    int j = idx[bmk];
    float4 pv = pp4[(size_t)b * Np + j];
    const float* qp = q + (size_t)bm * 3;
    float h0 = pv.x - qp[0], h1 = pv.y - qp[1], h2 = pv.z - qp[2];
    phat[(size_t)bmk * 3 + 0] = h0;
    phat[(size_t)bmk * 3 + 1] = h1;
    phat[(size_t)bmk * 3 + 2] = h2;
    a[0] += h0; a[1] += h1; a[2] += h2;
    a[3] += h0 * h0; a[4] += h1 * h1; a[5] += h2 * h2;
    a[6] += h0 * h1; a[7] += h0 * h2; a[8] += h1 * h2;
  }
#pragma unroll
  for (int off = 32; off > 0; off >>= 1)
#pragma unroll
    for (int k = 0; k < 9; ++k) a[k] += __shfl_down(a[k], off);
  __shared__ float ls[9];
  if (tid < 9) ls[tid] = 0.f;
  __syncthreads();
  if ((tid & 63) == 0)
    for (int k = 0; k < 9; ++k) atomicAdd(&ls[k], a[k]);
  __syncthreads();
  if (tid < 9) atomicAdd(&stats[tid], ls[tid]);
}

// ---------------- pre2 channel stats, two-phase through LDS
__global__ __launch_bounds__(256) void stats2_kernel(const float* __restrict__ phat,
                                                     const float* __restrict__ stats,
                                                     const float* __restrict__ W1,
                                                     const float* __restrict__ b1,
                                                     const float* __restrict__ g1,
                                                     const float* __restrict__ be1,
                                                     const float* __restrict__ W2,
                                                     const float* __restrict__ b2,
                                                     float* __restrict__ stats2) {
  __shared__ float hsh[256 * 36];
  __shared__ float w2s[32 * 33];
  __shared__ float w1s[96], sc1[32], sh1[32], b2s[32], ls[64];
  int tid = threadIdx.x;
  if (tid < 32) {
    bn1_compute(tid, stats, W1, b1, g1, be1, &sc1[tid], &sh1[tid]);
    b2s[tid] = b2[tid];
  }
  if (tid < 96) w1s[tid] = W1[tid];
  if (tid < 64) ls[tid] = 0.f;
  for (int e = tid; e < 1024; e += 256) w2s[(e >> 5) * 33 + (e & 31)] = W2[e];
  __syncthreads();
  {
    int bmk = blockIdx.x * 256 + tid;
    float h0 = phat[(size_t)bmk * 3], hy = phat[(size_t)bmk * 3 + 1], hz = phat[(size_t)bmk * 3 + 2];
#pragma unroll
    for (int o4 = 0; o4 < 8; ++o4) {
      float4 r;
      float* rp = (float*)&r;
#pragma unroll
      for (int u = 0; u < 4; ++u) {
        int o = o4 * 4 + u;
        float t = w1s[3 * o] * h0 + w1s[3 * o + 1] * hy + w1s[3 * o + 2] * hz;
        rp[u] = fmaxf(0.f, t * sc1[o] + sh1[o]);
      }
      *(float4*)&hsh[tid * 36 + o4 * 4] = r;
    }
  }
  __syncthreads();
  int oc = tid & 31, grp = tid >> 5;
  float wrow[32];
#pragma unroll
  for (int c = 0; c < 32; ++c) wrow[c] = w2s[oc * 33 + c];
  float bias = b2s[oc];
  float ss = 0.f, qq = 0.f;
  for (int r = 0; r < 32; ++r) {
    int row = grp * 32 + r;
    float a = bias;
    const float4* hr = (const float4*)&hsh[row * 36];
#pragma unroll
    for (int c4 = 0; c4 < 8; ++c4) {
      float4 hv = hr[c4];
      a += hv.x * wrow[c4 * 4 + 0];
      a += hv.y * wrow[c4 * 4 + 1];
      a += hv.z * wrow[c4 * 4 + 2];
      a += hv.w * wrow[c4 * 4 + 3];
    }
    ss += a;
    qq += a * a;
  }
  atomicAdd(&ls[oc], ss);
  atomicAdd(&ls[32 + oc], qq);
  __syncthreads();
  if (tid < 64) atomicAdd(&stats2[tid], ls[tid]);
}

// ---------------- stn conv + fused output stats
__global__ __launch_bounds__(256) void stn1_kernel(const float* __restrict__ phat,
                                                   const float* __restrict__ Ws1,
                                                   const float* __restrict__ bs1,
                                                   float* __restrict__ pt1,
                                                   float* __restrict__ spt1) {
  __shared__ float w[256 * 49];
  __shared__ float ph[32 * 48];
  int tid = threadIdx.x;
  int bm0 = blockIdx.x * 32;
  for (int e = tid; e < 256 * 48; e += 256) w[(e / 48) * 49 + (e % 48)] = Ws1[e];
  for (int e = tid; e < 32 * 48; e += 256) ph[e] = phat[(size_t)bm0 * 48 + e];
  __syncthreads();
  int o = tid;
  float acc[32];
  float bias = bs1[o];
#pragma unroll
  for (int j = 0; j < 32; ++j) acc[j] = bias;
#pragma unroll
  for (int c = 0; c < 3; ++c)
#pragma unroll
    for (int k = 0; k < 16; ++k) {
      float wv = w[o * 49 + c * 16 + k];
#pragma unroll
      for (int j = 0; j < 32; ++j) acc[j] += ph[j * 48 + k * 3 + c] * wv;
    }
  float s = 0.f, s2 = 0.f;
  for (int j = 0; j < 32; ++j) {
    pt1[(size_t)(bm0 + j) * 256 + o] = acc[j];
    s += acc[j];
    s2 += acc[j] * acc[j];
  }
  atomicAdd(&spt1[o], s);
  atomicAdd(&spt1[256 + o], s2);
}

// ---------------- MFMA GEMM 64x128, grid 512
__global__ __launch_bounds__(256) void stn_mm_kernel(const float* __restrict__ in,
                                                     const float* __restrict__ sums,
                                                     const float* __restrict__ gg,
                                                     const float* __restrict__ be,
                                                     const float* __restrict__ W,
                                                     const float* __restrict__ bias,
                                                     float* __restrict__ out,
                                                     float* __restrict__ outstats,
                                                     int do_stats) {
  __shared__ unsigned short As[64 * 40], Bs[128 * 40];
  __shared__ float scA[256], shA[256], ls[256];
  int tid = threadIdx.x;
  ls[tid] = 0.f;
  {
    float n = (float)BM;
    float mean = sums[tid] / n;
    float var = sums[256 + tid] / n - mean * mean;
    float s = gg[tid] * rsqrtf(var + EPS);
    scA[tid] = s;
    shA[tid] = be[tid] - mean * s;
  }
  int mb = blockIdx.x >> 1, nb = blockIdx.x & 1;
  int bm0 = mb * 64, o0 = nb * 128;
  int wid = tid >> 6, lane = tid & 63;
  int wm = wid >> 1, wn = wid & 1;
  int mh = lane & 15, quad = lane >> 4;
  f32x4 acc[2][4];
#pragma unroll
  for (int a = 0; a < 2; ++a)
#pragma unroll
    for (int bq = 0; bq < 4; ++bq) acc[a][bq] = (f32x4){0.f, 0.f, 0.f, 0.f};
  int ar = tid >> 2, aseg = tid & 3;
  const float* Ag = in + (size_t)(bm0 + ar) * 256 + aseg * 8;
  int aoff = ar * 40 + aseg * 8;
  int ci = aseg * 8;
  for (int i0 = 0; i0 < 256; i0 += 32) {
    __syncthreads();
    float4 v0 = *(const float4*)(Ag + i0);
    float4 v1 = *(const float4*)(Ag + i0 + 4);
    float av[8] = {v0.x, v0.y, v0.z, v0.w, v1.x, v1.y, v1.z, v1.w};
    short8 ap;
#pragma unroll
    for (int k = 0; k < 8; ++k)
      ap[k] = (short)f2bf(fmaxf(0.f, av[k] * scA[i0 + ci + k] + shA[i0 + ci + k]));
    *(short8*)&As[aoff] = ap;
#pragma unroll
    for (int jb = 0; jb < 2; ++jb) {
      int br = jb * 64 + ar;
      const float* Bg = W + (size_t)(o0 + br) * 256 + aseg * 8;
      float4 u0 = *(const float4*)(Bg + i0);
      float4 u1 = *(const float4*)(Bg + i0 + 4);
      float bv[8] = {u0.x, u0.y, u0.z, u0.w, u1.x, u1.y, u1.z, u1.w};
      short8 bp;
#pragma unroll
      for (int k = 0; k < 8; ++k) bp[k] = (short)f2bf(bv[k]);
      *(short8*)&Bs[br * 40 + aseg * 8] = bp;
    }
    __syncthreads();
#pragma unroll
    for (int mt = 0; mt < 2; ++mt) {
      short8 af = *(const short8*)&As[(wm * 32 + mt * 16 + mh) * 40 + quad * 8];
#pragma unroll
      for (int nt = 0; nt < 4; ++nt) {
        short8 bf = *(const short8*)&Bs[(wn * 64 + nt * 16 + mh) * 40 + quad * 8];
        acc[mt][nt] = __builtin_amdgcn_mfma_f32_16x16x32_bf16(af, bf, acc[mt][nt], 0, 0, 0);
      }
    }
  }
#pragma unroll
  for (int mt = 0; mt < 2; ++mt)
#pragma unroll
    for (int nt = 0; nt < 4; ++nt) {
      int colL = wn * 64 + nt * 16 + mh;
      int col = o0 + colL;
      float bvv = bias[col];
      float ps = 0.f, pq = 0.f;
#pragma unroll
      for (int r = 0; r < 4; ++r) {
        float val = acc[mt][nt][r] + bvv;
        out[(size_t)(bm0 + wm * 32 + mt * 16 + quad * 4 + r) * 256 + col] = val;
        ps += val;
        pq += val * val;
      }
      if (do_stats) {
        atomicAdd(&ls[colL], ps);
        atomicAdd(&ls[128 + colL], pq);
      }
    }
  if (do_stats) {
    __syncthreads();
    if (tid < 128) {
      atomicAdd(&outstats[o0 + tid], ls[tid]);
      atomicAdd(&outstats[256 + o0 + tid], ls[128 + tid]);
    }
  }
}

// ---------------- recompute h2 from phat, build x_hat (bf16 LDS), x2 = T @ x_hat
__global__ __launch_bounds__(256) void xhat_x2_kernel(const float* __restrict__ phat,
                                                      const float* __restrict__ stats,
                                                      const float* __restrict__ stats2,
                                                      const float* __restrict__ W1,
                                                      const float* __restrict__ b1,
                                                      const float* __restrict__ g1,
                                                      const float* __restrict__ be1,
                                                      const float* __restrict__ W2,
                                                      const float* __restrict__ b2,
                                                      const float* __restrict__ g2,
                                                      const float* __restrict__ be2,
                                                      const float* __restrict__ xt,
                                                      const int* __restrict__ idx,
                                                      const float* __restrict__ Tbuf,
                                                      unsigned short* __restrict__ x2) {
  __shared__ unsigned short xh[256 * 98];
  __shared__ float w1s[96], w2s[32 * 33], sc1[32], sh1[32], sc2[32], sh2[32];
  int tid = threadIdx.x;
  if (tid < 32) {
    bn1_compute(tid, stats, W1, b1, g1, be1, &sc1[tid], &sh1[tid]);
    float n = (float)BMK;
    float mean = stats2[tid] / n;
    float var = stats2[32 + tid] / n - mean * mean;
    float s = g2[tid] * rsqrtf(var + EPS);
    sc2[tid] = s;
    sh2[tid] = be2[tid] - mean * s + b2[tid] * s;
  }
  if (tid < 96) w1s[tid] = W1[tid];
  for (int e = tid; e < 1024; e += 256) w2s[(e >> 5) * 33 + (e & 31)] = W2[e];
  __syncthreads();
  int bm0 = blockIdx.x * 16;
  int b = bm0 >> 11;
  int bml = tid >> 4, j = tid & 15;
  int bmk = (bm0 + bml) * 16 + j;
  int row = tid * 98;
  {
    float h0 = phat[(size_t)bmk * 3], hy = phat[(size_t)bmk * 3 + 1], hz = phat[(size_t)bmk * 3 + 2];
    float h1[32];
#pragma unroll
    for (int o = 0; o < 32; ++o) {
      float t = w1s[3 * o] * h0 + w1s[3 * o + 1] * hy + w1s[3 * o + 2] * hz;
      h1[o] = fmaxf(0.f, t * sc1[o] + sh1[o]);
    }
#pragma unroll
    for (int o4 = 0; o4 < 8; ++o4) {
      float r[4];
#pragma unroll
      for (int u = 0; u < 4; ++u) {
        int o = o4 * 4 + u;
        float a = 0.f;
#pragma unroll
        for (int c = 0; c < 32; ++c) a += h1[c] * w2s[o * 33 + c];
        r[u] = fmaxf(0.f, a * sc2[o] + sh2[o]);
      }
      *(unsigned*)&xh[row + o4 * 4] = (unsigned)f2bf(r[0]) | (((unsigned)f2bf(r[1])) << 16);
      *(unsigned*)&xh[row + o4 * 4 + 2] = (unsigned)f2bf(r[2]) | (((unsigned)f2bf(r[3])) << 16);
    }
    int jx = idx[bmk];
    const float4* xr = (const float4*)(xt + ((size_t)b * Np + jx) * 64);
#pragma unroll
    for (int c4 = 0; c4 < 16; ++c4) {
      float4 v = xr[c4];
      *(unsigned*)&xh[row + 32 + c4 * 4] = (unsigned)f2bf(v.x) | (((unsigned)f2bf(v.y)) << 16);
      *(unsigned*)&xh[row + 32 + c4 * 4 + 2] = (unsigned)f2bf(v.z) | (((unsigned)f2bf(v.w)) << 16);
    }
  }
  float Tr[16];
  {
    const float4* tg = (const float4*)(Tbuf + (size_t)(bm0 + bml) * 256 + j * 16);
#pragma unroll
    for (int w4 = 0; w4 < 4; ++w4) {
      float4 tv = tg[w4];
      Tr[w4 * 4 + 0] = tv.x; Tr[w4 * 4 + 1] = tv.y;
      Tr[w4 * 4 + 2] = tv.z; Tr[w4 * 4 + 3] = tv.w;
    }
  }
  __syncthreads();
#pragma unroll
  for (int c0 = 0; c0 < 96; c0 += 32) {
    float acc[32];
#pragma unroll
    for (int cc = 0; cc < 32; ++cc) acc[cc] = 0.f;
#pragma unroll
    for (int jj = 0; jj < 16; ++jj) {
      const unsigned* xr2 = (const unsigned*)&xh[(bml * 16 + jj) * 98 + c0];
      float t = Tr[jj];
#pragma unroll
      for (int cc = 0; cc < 16; ++cc) {
        unsigned uv = xr2[cc];
        acc[cc * 2] += t * bf2f_lo(uv);
        acc[cc * 2 + 1] += t * bf2f_hi(uv);
      }
    }
    unsigned* dst = (unsigned*)(x2 + (size_t)bmk * 96 + c0);
#pragma unroll
    for (int cc = 0; cc < 16; ++cc)
      dst[cc] = (unsigned)f2bf(acc[cc * 2]) | (((unsigned)f2bf(acc[cc * 2 + 1])) << 16);
  }
}

// ---------------- preout = x2(bf16) @ Wcrp^T + bc, MFMA 64x128, fused stats
__global__ __launch_bounds__(256) void preout_kernel(const unsigned short* __restrict__ x2,
                                                     const unsigned short* __restrict__ Wcrp,
                                                     const float* __restrict__ bc,
                                                     float* __restrict__ pout,
                                                     float* __restrict__ spout) {
  __shared__ unsigned short As[64 * 40], Bs[128 * 40];
  __shared__ float ls[256];
  int tid = threadIdx.x;
  ls[tid] = 0.f;
  int bm0 = blockIdx.x * 64;
  int wid = tid >> 6, lane = tid & 63;
  int wm = wid >> 1, wn = wid & 1;
  int mh = lane & 15, quad = lane >> 4;
  f32x4 acc[2][4];
#pragma unroll
  for (int a = 0; a < 2; ++a)
#pragma unroll
    for (int bq = 0; bq < 4; ++bq) acc[a][bq] = (f32x4){0.f, 0.f, 0.f, 0.f};
  int ar = tid >> 2, aseg = tid & 3;
  const unsigned short* Ag = x2 + (size_t)(bm0 + ar) * 1536 + aseg * 8;
  const unsigned short* Bg0 = Wcrp + (size_t)ar * 1536 + aseg * 8;
  const unsigned short* Bg1 = Wcrp + (size_t)(64 + ar) * 1536 + aseg * 8;
  int aoff = ar * 40 + aseg * 8;
  short8 a_pre = *(const short8*)Ag;
  short8 b_pre0 = *(const short8*)Bg0;
  short8 b_pre1 = *(const short8*)Bg1;
  for (int i0 = 0; i0 < 1536; i0 += 32) {
    __syncthreads();
    *(short8*)&As[aoff] = a_pre;
    *(short8*)&Bs[aoff] = b_pre0;
    *(short8*)&Bs[64 * 40 + aoff] = b_pre1;
    __syncthreads();
    if (i0 + 32 < 1536) {
      a_pre = *(const short8*)(Ag + i0 + 32);
      b_pre0 = *(const short8*)(Bg0 + i0 + 32);
      b_pre1 = *(const short8*)(Bg1 + i0 + 32);
    }
#pragma unroll
    for (int mt = 0; mt < 2; ++mt) {
      short8 af = *(const short8*)&As[(wm * 32 + mt * 16 + mh) * 40 + quad * 8];
#pragma unroll
      for (int nt = 0; nt < 4; ++nt) {
        short8 bf = *(const short8*)&Bs[(wn * 64 + nt * 16 + mh) * 40 + quad * 8];
        acc[mt][nt] = __builtin_amdgcn_mfma_f32_16x16x32_bf16(af, bf, acc[mt][nt], 0, 0, 0);
      }
    }
  }
#pragma unroll
  for (int mt = 0; mt < 2; ++mt)
#pragma unroll
    for (int nt = 0; nt < 4; ++nt) {
      int col = wn * 64 + nt * 16 + mh;
      float bvv = bc[col];
      float ps = 0.f, pq = 0.f;
#pragma unroll
      for (int r = 0; r < 4; ++r) {
        float val = acc[mt][nt][r] + bvv;
        pout[(size_t)(bm0 + wm * 32 + mt * 16 + quad * 4 + r) * 128 + col] = val;
        ps += val;
        pq += val * val;
      }
      atomicAdd(&ls[col], ps);
      atomicAdd(&ls[128 + col], pq);
    }
  __syncthreads();
  atomicAdd(&spout[tid], ls[tid]);
}

// ---------------- epilogue: blocks [0,192) copy q; [192,448) transpose+BN via LDS
__global__ __launch_bounds__(256) void final_kernel(const float* __restrict__ q,
                                                    const float* __restrict__ pout,
                                                    const float* __restrict__ scs,
                                                    const float* __restrict__ gc,
                                                    const float* __restrict__ bec,
                                                    float* __restrict__ dout) {
  __shared__ float ldsT[128 * 65];
  int blk = blockIdx.x;
  int tid = threadIdx.x;
  if (blk < 192) {
    int g = blk * 256 + tid;
    dout[g] = q[g];
    return;
  }
  int blk2 = blk - 192;
  int b = blk2 >> 5;
  int m0 = (blk2 & 31) * 64;
  int row = tid >> 2, seg = tid & 3;
  const float4* src = (const float4*)(pout + ((size_t)(b * Mq) + m0 + row) * 128 + seg * 32);
#pragma unroll
  for (int k4 = 0; k4 < 8; ++k4) {
    float4 v = src[k4];
    int o = seg * 32 + k4 * 4;
    ldsT[(o + 0) * 65 + row] = v.x;
    ldsT[(o + 1) * 65 + row] = v.y;
    ldsT[(o + 2) * 65 + row] = v.z;
    ldsT[(o + 3) * 65 + row] = v.w;
  }
  __syncthreads();
  int lane = tid & 63, wv = tid >> 6;
  float n = (float)BM;
  float* base = dout + (size_t)BM * 3 + (size_t)b * COUT * Mq + m0;
#pragma unroll
  for (int rep = 0; rep < 32; ++rep) {
    int o = wv * 32 + rep;
    float mean = scs[o] / n;
    float var = scs[128 + o] / n - mean * mean;
    float s = gc[o] * rsqrtf(var + EPS);
    float shv = bec[o] - mean * s;
    float v = ldsT[o * 65 + lane];
    base[(size_t)o * Mq + lane] = fmaxf(0.f, v * s + shv);
  }
}

extern "C" void kernel_launch(void* const* d_in, const int* in_sizes, int n_in, void* d_out,
                              int out_size, void* d_ws, size_t ws_size, hipStream_t stream) {
  const float* p = (const float*)d_in[0];
  const float* q = (const float*)d_in[1];
  const float* x = (const float*)d_in[2];
  const float* W1 = (const float*)d_in[3];
  const float* b1 = (const float*)d_in[4];
  const float* g1 = (const float*)d_in[5];
  const float* be1 = (const float*)d_in[6];
  const float* W2 = (const float*)d_in[7];
  const float* b2 = (const float*)d_in[8];
  const float* g2 = (const float*)d_in[9];
  const float* be2 = (const float*)d_in[10];
  const float* Ws1 = (const float*)d_in[11];
  const float* bs1 = (const float*)d_in[12];
  const float* gs1 = (const float*)d_in[13];
  const float* bes1 = (const float*)d_in[14];
  const float* Ws2 = (const float*)d_in[15];
  const float* bs2 = (const float*)d_in[16];
  const float* gs2 = (const float*)d_in[17];
  const float* bes2 = (const float*)d_in[18];
  const float* Ws3 = (const float*)d_in[19];
  const float* bs3 = (const float*)d_in[20];
  const float* Wc = (const float*)d_in[21];
  const float* bc = (const float*)d_in[22];
  const float* gc = (const float*)d_in[23];
  const float* bec = (const float*)d_in[24];
  float* dout = (float*)d_out;

  char* ws = (char*)d_ws;
  float* stats = (float*)ws;  // s1(9)@0, s2(64)@16, spt1@128, spt2@640, spout@1152
  size_t off = 8192;
  float4* pp4 = (float4*)(ws + off);  off += (size_t)Bb * Np * 16;      // 1 MB
  int* idxb = (int*)(ws + off);       off += (size_t)BMK * 4;           // 1 MB
  float* xt = (float*)(ws + off);     off += (size_t)Bb * Np * 64 * 4;  // 16 MB
  float* phat = (float*)(ws + off);   off += (size_t)BMK * 3 * 4;       // 3 MB
  float* pt1 = (float*)(ws + off);    off += (size_t)BM * 256 * 4;      // 16 MB
  float* pt2 = (float*)(ws + off);    off += (size_t)BM * 256 * 4;      // 16 MB
  float* Tb = (float*)(ws + off);     off += (size_t)BM * 256 * 4;      // 16 MB
  float* pout = (float*)(ws + off);   off += (size_t)BM * 128 * 4;      // 8 MB
  unsigned short* wcrp = (unsigned short*)(ws + off); off += (size_t)1536 * 128 * 2;
  unsigned short* x2 = (unsigned short*)(ws + off);   off += (size_t)BM * 1536 * 2;  // 48 MB
  int* hist = (int*)(ws + off);       off += (size_t)Bb * NC * 4;       // 128 KB
  int* cursor = (int*)(ws + off);     off += (size_t)Bb * NC * 4;       // 128 KB
  int* cellstart = (int*)(ws + off);  off += (size_t)Bb * (NC + 1) * 4; // ~128 KB
  float4* sp4 = (float4*)(ws + off);  off += (size_t)Bb * Np * 16;      // 1 MB
  int* sidx = (int*)(ws + off);       off += (size_t)Bb * Np * 4;       // 256 KB

  hipMemsetAsync(stats, 0, 8192, stream);
  hipMemsetAsync(hist, 0, (size_t)Bb * NC * 4, stream);
  hipLaunchKernelGGL(prep_kernel, dim3(2048), dim3(256), 0, stream, p, x, Wc, pp4, xt, wcrp, hist);
  hipLaunchKernelGGL(prefix_kernel, dim3(8), dim3(256), 0, stream, hist, cellstart, cursor);
  hipLaunchKernelGGL(scatter_kernel, dim3(256), dim3(256), 0, stream, pp4, cursor, sp4, sidx);
  hipLaunchKernelGGL(knn_kernel, dim3(4096), dim3(256), 0, stream, sp4, sidx, cellstart, q, idxb);
  hipLaunchKernelGGL(phat_stats_kernel, dim3(256), dim3(256), 0, stream, pp4, q, idxb, phat, stats);
  hipLaunchKernelGGL(stn1_kernel, dim3(512), dim3(256), 0, stream, phat, Ws1, bs1, pt1, stats + 128);
  hipLaunchKernelGGL(stats2_kernel, dim3(1024), dim3(256), 0, stream, phat, stats, W1, b1, g1, be1, W2, b2, stats + 16);
  hipLaunchKernelGGL(stn_mm_kernel, dim3(512), dim3(256), 0, stream, pt1, stats + 128, gs1, bes1, Ws2, bs2, pt2, stats + 640, 1);
  hipLaunchKernelGGL(stn_mm_kernel, dim3(512), dim3(256), 0, stream, pt2, stats + 640, gs2, bes2, Ws3, bs3, Tb, (float*)nullptr, 0);
  hipLaunchKernelGGL(xhat_x2_kernel, dim3(1024), dim3(256), 0, stream, phat, stats, stats + 16,
                     W1, b1, g1, be1, W2, b2, g2, be2, xt, idxb, Tb, x2);
  hipLaunchKernelGGL(preout_kernel, dim3(256), dim3(256), 0, stream, x2, wcrp, bc, pout, stats + 1152);
  hipLaunchKernelGGL(final_kernel, dim3(448), dim3(256), 0, stream, q, pout, stats + 1152, gc, bec, dout);
}

// Round 13
// 495.196 us; speedup vs baseline: 1.3890x; 1.3890x over previous
//
#include <hip/hip_runtime.h>
#include <hip/hip_bf16.h>

// Round 13: hybrid kNN — R11's brute-force scan (bit-identical math/selection)
// with tau seeded from the query's own grid cell (grid build kernels verified
// in R12). Seed list is discarded (only tau survives) -> no duplicate hazard;
// tau is min-guarded so it is always an upper bound on the true 16th distance.
// Rest of pipeline identical to R11/R12.

#define EPS 1e-5f

constexpr int Bb   = 8;
constexpr int Np   = 8192;
constexpr int Mq   = 2048;
constexpr int COUT = 128;
constexpr int BM   = Bb * Mq;        // 16384
constexpr int BMK  = BM * 16;        // 262144
constexpr int GC   = 16;
constexpr int NC   = GC * GC * GC;   // 4096

typedef __attribute__((ext_vector_type(8))) short short8;
typedef __attribute__((ext_vector_type(4))) float f32x4;

__device__ __forceinline__ unsigned short f2bf(float x) {
  unsigned u = __float_as_uint(x);
  u += 0x7fffu + ((u >> 16) & 1u);
  return (unsigned short)(u >> 16);
}
__device__ __forceinline__ float bf2f_lo(unsigned v) { return __uint_as_float(v << 16); }
__device__ __forceinline__ float bf2f_hi(unsigned v) { return __uint_as_float(v & 0xffff0000u); }

__device__ __forceinline__ int cell_of(float c) {
  int v = (int)floorf(c * 2.0f + 8.0f);
  return v < 0 ? 0 : (v > 15 ? 15 : v);
}

// stats float offsets: s1(9)@0, s2(64)@16, spt1(512)@128, spt2(512)@640, spout(256)@1152

__device__ __forceinline__ void bn1_compute(int o, const float* __restrict__ st,
                                            const float* __restrict__ W1,
                                            const float* __restrict__ b1,
                                            const float* __restrict__ g1,
                                            const float* __restrict__ be1,
                                            float* sc_out, float* shf_out) {
  float n = (float)BMK;
  float w0 = W1[3 * o], w1 = W1[3 * o + 1], w2 = W1[3 * o + 2], b = b1[o];
  float s0 = st[0], s1 = st[1], s2 = st[2];
  float m00 = st[3], m11 = st[4], m22 = st[5], m01 = st[6], m02 = st[7], m12 = st[8];
  float ws = (w0 * s0 + w1 * s1 + w2 * s2) / n;
  float mean = b + ws;
  float quad = w0 * w0 * m00 + w1 * w1 * m11 + w2 * w2 * m22 +
               2.f * (w0 * w1 * m01 + w0 * w2 * m02 + w1 * w2 * m12);
  float ex2 = quad / n + 2.f * b * ws + b * b;
  float var = ex2 - mean * mean;
  float sc = g1[o] * rsqrtf(var + EPS);
  *sc_out = sc;
  *shf_out = be1[o] - mean * sc + b * sc;
}

// ---------------- fused prep: pack pts (+cell histogram) | transpose x | Wc repack
__global__ __launch_bounds__(256) void prep_kernel(const float* __restrict__ p,
                                                   const float* __restrict__ x,
                                                   const float* __restrict__ Wc,
                                                   float4* __restrict__ pp4,
                                                   float* __restrict__ xt,
                                                   unsigned short* __restrict__ wcrp,
                                                   int* __restrict__ hist) {
  __shared__ float tile[64][65];
  int blk = blockIdx.x;
  int tid = threadIdx.x;
  if (blk < 256) {
    int i = blk * 256 + tid;  // < 65536
    float px = p[3 * i], py = p[3 * i + 1], pz = p[3 * i + 2];
    float pp = __fadd_rn(__fadd_rn(__fmul_rn(px, px), __fmul_rn(py, py)), __fmul_rn(pz, pz));
    pp4[i] = make_float4(px, py, pz, pp);
    int b = i >> 13;
    int cid = (cell_of(px) << 8) | (cell_of(py) << 4) | cell_of(pz);
    atomicAdd(&hist[b * NC + cid], 1);
  } else if (blk < 1280) {
    int bx = blk - 256;
    int b = bx >> 7;
    int n0 = (bx & 127) << 6;
    int nl = tid & 63;
    int r0 = tid >> 6;
    const float* xb = x + (size_t)b * 64 * Np;
    for (int c = r0; c < 64; c += 4) tile[c][nl] = xb[(size_t)c * Np + n0 + nl];
    __syncthreads();
    float* xtb = xt + (size_t)b * Np * 64;
    for (int n = r0; n < 64; n += 4) xtb[(size_t)(n0 + n) * 64 + nl] = tile[nl][n];
  } else {
    int g = (blk - 1280) * 256 + tid;
    if (g < 128 * 1536) {
      int o = g / 1536, r = g % 1536;
      int c = r % 96, j = r / 96;
      wcrp[g] = f2bf(Wc[(size_t)o * 1536 + c * 16 + j]);
    }
  }
}

// ---------------- exclusive prefix over 4096 cells per batch
__global__ __launch_bounds__(256) void prefix_kernel(const int* __restrict__ hist,
                                                     int* __restrict__ cellstart,
                                                     int* __restrict__ cursor) {
  __shared__ int ls[256];
  int b = blockIdx.x, t = threadIdx.x;
  const int* h = hist + b * NC;
  int loc[16], s = 0;
#pragma unroll
  for (int k = 0; k < 16; ++k) { loc[k] = h[t * 16 + k]; s += loc[k]; }
  ls[t] = s;
  __syncthreads();
  for (int off = 1; off < 256; off <<= 1) {
    int v = (t >= off) ? ls[t - off] : 0;
    __syncthreads();
    ls[t] += v;
    __syncthreads();
  }
  int run = ls[t] - s;
  int* cs = cellstart + b * (NC + 1);
  int* cu = cursor + b * NC;
#pragma unroll
  for (int k = 0; k < 16; ++k) {
    cs[t * 16 + k] = run;
    cu[t * 16 + k] = run;
    run += loc[k];
  }
  if (t == 255) cs[NC] = run;
}

// ---------------- scatter points into cell-sorted arrays
__global__ __launch_bounds__(256) void scatter_kernel(const float4* __restrict__ pp4,
                                                      int* __restrict__ cursor,
                                                      float4* __restrict__ sp4,
                                                      int* __restrict__ sidx) {
  int i = blockIdx.x * 256 + threadIdx.x;  // < 65536
  int b = i >> 13;
  float4 pv = pp4[i];
  int cid = (cell_of(pv.x) << 8) | (cell_of(pv.y) << 4) | cell_of(pv.z);
  int pos = atomicAdd(&cursor[b * NC + cid], 1);
  sp4[(size_t)b * Np + pos] = pv;
  sidx[(size_t)b * Np + pos] = i & 8191;
}

// ---------------- kNN: 2 queries/wave brute scan (R11-identical) + cell-seeded tau.
__global__ __launch_bounds__(256) void knn_kernel(const float4* __restrict__ pp4,
                                                  const float4* __restrict__ sp4,
                                                  const int* __restrict__ cellstart,
                                                  const float* __restrict__ q,
                                                  int* __restrict__ idx_out) {
  int tid = threadIdx.x;
  int wave = blockIdx.x * 4 + (tid >> 6);  // 0..8191
  int lane = tid & 63;
  int q0 = wave * 2;
  int b = q0 >> 11;  // 2 | 2048 -> both queries share b
  const float4* pb = pp4 + (size_t)b * Np;
  const float4* sp = sp4 + (size_t)b * Np;
  const int* cs = cellstart + b * (NC + 1);
  float qx[2], qy[2], qz[2], qqv[2];
#pragma unroll
  for (int j = 0; j < 2; ++j) {
    const float* qp = q + (size_t)(q0 + j) * 3;
    qx[j] = qp[0]; qy[j] = qp[1]; qz[j] = qp[2];
    qqv[j] = __fadd_rn(__fadd_rn(__fmul_rn(qx[j], qx[j]), __fmul_rn(qy[j], qy[j])),
                       __fmul_rn(qz[j], qz[j]));
  }
  unsigned long long key[2] = {~0ULL, ~0ULL};
  float tau_f[2] = {INFINITY, INFINITY};
  // ---- seed tau from own cell (list discarded afterwards; tau = upper bound
  //      on true 16th distance -> main-scan filter stays a certified superset)
#pragma unroll
  for (int j = 0; j < 2; ++j) {
    int cid = (cell_of(qx[j]) << 8) | (cell_of(qy[j]) << 4) | cell_of(qz[j]);
    int s0 = cs[cid], cnt = cs[cid + 1] - s0;
    for (int off = 0; off < cnt; off += 64) {
      int rel = off + lane;
      bool valid = rel < cnt;
      float4 pv = sp[s0 + (valid ? rel : 0)];
      float e = __fmaf_rn(qz[j], pv.z, __fmaf_rn(qy[j], pv.y, __fmul_rn(qx[j], pv.x)));
      float d = __fadd_rn(__fsub_rn(qqv[j], __fmul_rn(2.0f, e)), pv.w);
      if (!valid) d = __uint_as_float(0x7FC00000u);  // NaN fails d<=tau
      unsigned long long mask = __ballot(d <= tau_f[j]);
      if (mask) {
        unsigned uu = __float_as_uint(d);
        uu ^= ((unsigned)(((int)uu) >> 31)) | 0x80000000u;
        unsigned long long cand = (((unsigned long long)uu) << 32);  // idx bits unused
        do {
          int src = __ffsll((unsigned long long)mask) - 1;
          mask &= mask - 1;
          unsigned long long ck = __shfl(cand, src);
          unsigned long long up = __shfl_up(key[j], 1);
          if (lane == 0) up = 0ULL;
          if (lane < 16 && ck < key[j]) key[j] = (up > ck) ? up : ck;
        } while (mask);
        unsigned long long tau = __shfl(key[j], 15);
        unsigned tau_m = (unsigned)(tau >> 32);
        unsigned inv = tau_m ^ ((tau_m & 0x80000000u) ? 0x80000000u : 0xFFFFFFFFu);
        float tc = (tau_m == 0xFFFFFFFFu) ? INFINITY : __uint_as_float(inv);
        if (tc < tau_f[j]) tau_f[j] = tc;
      }
    }
    key[j] = ~0ULL;  // discard seed list, keep tau
  }
  // ---- main brute scan: byte-identical structure/order to R11
  for (int base = 0; base < Np; base += 256) {
    float4 pv[4];
#pragma unroll
    for (int u4 = 0; u4 < 4; ++u4) pv[u4] = pb[base + u4 * 64 + lane];
    float d[4][2];
#pragma unroll
    for (int u4 = 0; u4 < 4; ++u4)
#pragma unroll
      for (int j = 0; j < 2; ++j) {
        float e = __fmaf_rn(qz[j], pv[u4].z, __fmaf_rn(qy[j], pv[u4].y, __fmul_rn(qx[j], pv[u4].x)));
        d[u4][j] = __fadd_rn(__fsub_rn(qqv[j], __fmul_rn(2.0f, e)), pv[u4].w);
      }
#pragma unroll
    for (int u4 = 0; u4 < 4; ++u4)
#pragma unroll
      for (int j = 0; j < 2; ++j) {
        unsigned long long mask = __ballot(d[u4][j] <= tau_f[j]);
        if (mask) {
          int i = base + u4 * 64 + lane;
          unsigned uu = __float_as_uint(d[u4][j]);
          uu ^= ((unsigned)(((int)uu) >> 31)) | 0x80000000u;
          unsigned long long cand = (((unsigned long long)uu) << 32) | (unsigned)i;
          do {
            int src = __ffsll((unsigned long long)mask) - 1;
            mask &= mask - 1;
            unsigned long long ck = __shfl(cand, src);
            unsigned long long up = __shfl_up(key[j], 1);
            if (lane == 0) up = 0ULL;
            if (lane < 16 && ck < key[j]) key[j] = (up > ck) ? up : ck;
          } while (mask);
          unsigned long long tau = __shfl(key[j], 15);
          unsigned tau_m = (unsigned)(tau >> 32);
          unsigned inv = tau_m ^ ((tau_m & 0x80000000u) ? 0x80000000u : 0xFFFFFFFFu);
          float tc = (tau_m == 0xFFFFFFFFu) ? INFINITY : __uint_as_float(inv);
          if (tc < tau_f[j]) tau_f[j] = tc;
        }
      }
  }
  if (lane < 16) {
#pragma unroll
    for (int j = 0; j < 2; ++j)
      idx_out[(size_t)(q0 + j) * 16 + lane] = (int)(key[j] & 0xffffffffULL);
  }
}

// ---------------- gather phat + accumulate 9 phat moments
__global__ __launch_bounds__(256) void phat_stats_kernel(const float4* __restrict__ pp4,
                                                         const float* __restrict__ q,
                                                         const int* __restrict__ idx,
                                                         float* __restrict__ phat,
                                                         float* __restrict__ stats) {
  float a[9];
#pragma unroll
  for (int k = 0; k < 9; ++k) a[k] = 0.f;
  int tid = threadIdx.x;
  for (int it = 0; it < 4; ++it) {
    int bmk = blockIdx.x * 256 + tid + it * 65536;
    int bm = bmk >> 4;
    int b = bm >> 11;
    int j = idx[bmk];
    float4 pv = pp4[(size_t)b * Np + j];
    const float* qp = q + (size_t)bm * 3;
    float h0 = pv.x - qp[0], h1 = pv.y - qp[1], h2 = pv.z - qp[2];
    phat[(size_t)bmk * 3 + 0] = h0;
    phat[(size_t)bmk * 3 + 1] = h1;
    phat[(size_t)bmk * 3 + 2] = h2;
    a[0] += h0; a[1] += h1; a[2] += h2;
    a[3] += h0 * h0; a[4] += h1 * h1; a[5] += h2 * h2;
    a[6] += h0 * h1; a[7] += h0 * h2; a[8] += h1 * h2;
  }
#pragma unroll
  for (int off = 32; off > 0; off >>= 1)
#pragma unroll
    for (int k = 0; k < 9; ++k) a[k] += __shfl_down(a[k], off);
  __shared__ float ls[9];
  if (tid < 9) ls[tid] = 0.f;
  __syncthreads();
  if ((tid & 63) == 0)
    for (int k = 0; k < 9; ++k) atomicAdd(&ls[k], a[k]);
  __syncthreads();
  if (tid < 9) atomicAdd(&stats[tid], ls[tid]);
}

// ---------------- pre2 channel stats, two-phase through LDS
__global__ __launch_bounds__(256) void stats2_kernel(const float* __restrict__ phat,
                                                     const float* __restrict__ stats,
                                                     const float* __restrict__ W1,
                                                     const float* __restrict__ b1,
                                                     const float* __restrict__ g1,
                                                     const float* __restrict__ be1,
                                                     const float* __restrict__ W2,
                                                     const float* __restrict__ b2,
                                                     float* __restrict__ stats2) {
  __shared__ float hsh[256 * 36];
  __shared__ float w2s[32 * 33];
  __shared__ float w1s[96], sc1[32], sh1[32], b2s[32], ls[64];
  int tid = threadIdx.x;
  if (tid < 32) {
    bn1_compute(tid, stats, W1, b1, g1, be1, &sc1[tid], &sh1[tid]);
    b2s[tid] = b2[tid];
  }
  if (tid < 96) w1s[tid] = W1[tid];
  if (tid < 64) ls[tid] = 0.f;
  for (int e = tid; e < 1024; e += 256) w2s[(e >> 5) * 33 + (e & 31)] = W2[e];
  __syncthreads();
  {
    int bmk = blockIdx.x * 256 + tid;
    float h0 = phat[(size_t)bmk * 3], hy = phat[(size_t)bmk * 3 + 1], hz = phat[(size_t)bmk * 3 + 2];
#pragma unroll
    for (int o4 = 0; o4 < 8; ++o4) {
      float4 r;
      float* rp = (float*)&r;
#pragma unroll
      for (int u = 0; u < 4; ++u) {
        int o = o4 * 4 + u;
        float t = w1s[3 * o] * h0 + w1s[3 * o + 1] * hy + w1s[3 * o + 2] * hz;
        rp[u] = fmaxf(0.f, t * sc1[o] + sh1[o]);
      }
      *(float4*)&hsh[tid * 36 + o4 * 4] = r;
    }
  }
  __syncthreads();
  int oc = tid & 31, grp = tid >> 5;
  float wrow[32];
#pragma unroll
  for (int c = 0; c < 32; ++c) wrow[c] = w2s[oc * 33 + c];
  float bias = b2s[oc];
  float ss = 0.f, qq = 0.f;
  for (int r = 0; r < 32; ++r) {
    int row = grp * 32 + r;
    float a = bias;
    const float4* hr = (const float4*)&hsh[row * 36];
#pragma unroll
    for (int c4 = 0; c4 < 8; ++c4) {
      float4 hv = hr[c4];
      a += hv.x * wrow[c4 * 4 + 0];
      a += hv.y * wrow[c4 * 4 + 1];
      a += hv.z * wrow[c4 * 4 + 2];
      a += hv.w * wrow[c4 * 4 + 3];
    }
    ss += a;
    qq += a * a;
  }
  atomicAdd(&ls[oc], ss);
  atomicAdd(&ls[32 + oc], qq);
  __syncthreads();
  if (tid < 64) atomicAdd(&stats2[tid], ls[tid]);
}

// ---------------- stn conv + fused output stats
__global__ __launch_bounds__(256) void stn1_kernel(const float* __restrict__ phat,
                                                   const float* __restrict__ Ws1,
                                                   const float* __restrict__ bs1,
                                                   float* __restrict__ pt1,
                                                   float* __restrict__ spt1) {
  __shared__ float w[256 * 49];
  __shared__ float ph[32 * 48];
  int tid = threadIdx.x;
  int bm0 = blockIdx.x * 32;
  for (int e = tid; e < 256 * 48; e += 256) w[(e / 48) * 49 + (e % 48)] = Ws1[e];
  for (int e = tid; e < 32 * 48; e += 256) ph[e] = phat[(size_t)bm0 * 48 + e];
  __syncthreads();
  int o = tid;
  float acc[32];
  float bias = bs1[o];
#pragma unroll
  for (int j = 0; j < 32; ++j) acc[j] = bias;
#pragma unroll
  for (int c = 0; c < 3; ++c)
#pragma unroll
    for (int k = 0; k < 16; ++k) {
      float wv = w[o * 49 + c * 16 + k];
#pragma unroll
      for (int j = 0; j < 32; ++j) acc[j] += ph[j * 48 + k * 3 + c] * wv;
    }
  float s = 0.f, s2 = 0.f;
  for (int j = 0; j < 32; ++j) {
    pt1[(size_t)(bm0 + j) * 256 + o] = acc[j];
    s += acc[j];
    s2 += acc[j] * acc[j];
  }
  atomicAdd(&spt1[o], s);
  atomicAdd(&spt1[256 + o], s2);
}

// ---------------- MFMA GEMM 64x128, grid 512
__global__ __launch_bounds__(256) void stn_mm_kernel(const float* __restrict__ in,
                                                     const float* __restrict__ sums,
                                                     const float* __restrict__ gg,
                                                     const float* __restrict__ be,
                                                     const float* __restrict__ W,
                                                     const float* __restrict__ bias,
                                                     float* __restrict__ out,
                                                     float* __restrict__ outstats,
                                                     int do_stats) {
  __shared__ unsigned short As[64 * 40], Bs[128 * 40];
  __shared__ float scA[256], shA[256], ls[256];
  int tid = threadIdx.x;
  ls[tid] = 0.f;
  {
    float n = (float)BM;
    float mean = sums[tid] / n;
    float var = sums[256 + tid] / n - mean * mean;
    float s = gg[tid] * rsqrtf(var + EPS);
    scA[tid] = s;
    shA[tid] = be[tid] - mean * s;
  }
  int mb = blockIdx.x >> 1, nb = blockIdx.x & 1;
  int bm0 = mb * 64, o0 = nb * 128;
  int wid = tid >> 6, lane = tid & 63;
  int wm = wid >> 1, wn = wid & 1;
  int mh = lane & 15, quad = lane >> 4;
  f32x4 acc[2][4];
#pragma unroll
  for (int a = 0; a < 2; ++a)
#pragma unroll
    for (int bq = 0; bq < 4; ++bq) acc[a][bq] = (f32x4){0.f, 0.f, 0.f, 0.f};
  int ar = tid >> 2, aseg = tid & 3;
  const float* Ag = in + (size_t)(bm0 + ar) * 256 + aseg * 8;
  int aoff = ar * 40 + aseg * 8;
  int ci = aseg * 8;
  for (int i0 = 0; i0 < 256; i0 += 32) {
    __syncthreads();
    float4 v0 = *(const float4*)(Ag + i0);
    float4 v1 = *(const float4*)(Ag + i0 + 4);
    float av[8] = {v0.x, v0.y, v0.z, v0.w, v1.x, v1.y, v1.z, v1.w};
    short8 ap;
#pragma unroll
    for (int k = 0; k < 8; ++k)
      ap[k] = (short)f2bf(fmaxf(0.f, av[k] * scA[i0 + ci + k] + shA[i0 + ci + k]));
    *(short8*)&As[aoff] = ap;
#pragma unroll
    for (int jb = 0; jb < 2; ++jb) {
      int br = jb * 64 + ar;
      const float* Bg = W + (size_t)(o0 + br) * 256 + aseg * 8;
      float4 u0 = *(const float4*)(Bg + i0);
      float4 u1 = *(const float4*)(Bg + i0 + 4);
      float bv[8] = {u0.x, u0.y, u0.z, u0.w, u1.x, u1.y, u1.z, u1.w};
      short8 bp;
#pragma unroll
      for (int k = 0; k < 8; ++k) bp[k] = (short)f2bf(bv[k]);
      *(short8*)&Bs[br * 40 + aseg * 8] = bp;
    }
    __syncthreads();
#pragma unroll
    for (int mt = 0; mt < 2; ++mt) {
      short8 af = *(const short8*)&As[(wm * 32 + mt * 16 + mh) * 40 + quad * 8];
#pragma unroll
      for (int nt = 0; nt < 4; ++nt) {
        short8 bf = *(const short8*)&Bs[(wn * 64 + nt * 16 + mh) * 40 + quad * 8];
        acc[mt][nt] = __builtin_amdgcn_mfma_f32_16x16x32_bf16(af, bf, acc[mt][nt], 0, 0, 0);
      }
    }
  }
#pragma unroll
  for (int mt = 0; mt < 2; ++mt)
#pragma unroll
    for (int nt = 0; nt < 4; ++nt) {
      int colL = wn * 64 + nt * 16 + mh;
      int col = o0 + colL;
      float bvv = bias[col];
      float ps = 0.f, pq = 0.f;
#pragma unroll
      for (int r = 0; r < 4; ++r) {
        float val = acc[mt][nt][r] + bvv;
        out[(size_t)(bm0 + wm * 32 + mt * 16 + quad * 4 + r) * 256 + col] = val;
        ps += val;
        pq += val * val;
      }
      if (do_stats) {
        atomicAdd(&ls[colL], ps);
        atomicAdd(&ls[128 + colL], pq);
      }
    }
  if (do_stats) {
    __syncthreads();
    if (tid < 128) {
      atomicAdd(&outstats[o0 + tid], ls[tid]);
      atomicAdd(&outstats[256 + o0 + tid], ls[128 + tid]);
    }
  }
}

// ---------------- recompute h2 from phat, build x_hat (bf16 LDS), x2 = T @ x_hat
__global__ __launch_bounds__(256) void xhat_x2_kernel(const float* __restrict__ phat,
                                                      const float* __restrict__ stats,
                                                      const float* __restrict__ stats2,
                                                      const float* __restrict__ W1,
                                                      const float* __restrict__ b1,
                                                      const float* __restrict__ g1,
                                                      const float* __restrict__ be1,
                                                      const float* __restrict__ W2,
                                                      const float* __restrict__ b2,
                                                      const float* __restrict__ g2,
                                                      const float* __restrict__ be2,
                                                      const float* __restrict__ xt,
                                                      const int* __restrict__ idx,
                                                      const float* __restrict__ Tbuf,
                                                      unsigned short* __restrict__ x2) {
  __shared__ unsigned short xh[256 * 98];
  __shared__ float w1s[96], w2s[32 * 33], sc1[32], sh1[32], sc2[32], sh2[32];
  int tid = threadIdx.x;
  if (tid < 32) {
    bn1_compute(tid, stats, W1, b1, g1, be1, &sc1[tid], &sh1[tid]);
    float n = (float)BMK;
    float mean = stats2[tid] / n;
    float var = stats2[32 + tid] / n - mean * mean;
    float s = g2[tid] * rsqrtf(var + EPS);
    sc2[tid] = s;
    sh2[tid] = be2[tid] - mean * s + b2[tid] * s;
  }
  if (tid < 96) w1s[tid] = W1[tid];
  for (int e = tid; e < 1024; e += 256) w2s[(e >> 5) * 33 + (e & 31)] = W2[e];
  __syncthreads();
  int bm0 = blockIdx.x * 16;
  int b = bm0 >> 11;
  int bml = tid >> 4, j = tid & 15;
  int bmk = (bm0 + bml) * 16 + j;
  int row = tid * 98;
  {
    float h0 = phat[(size_t)bmk * 3], hy = phat[(size_t)bmk * 3 + 1], hz = phat[(size_t)bmk * 3 + 2];
    float h1[32];
#pragma unroll
    for (int o = 0; o < 32; ++o) {
      float t = w1s[3 * o] * h0 + w1s[3 * o + 1] * hy + w1s[3 * o + 2] * hz;
      h1[o] = fmaxf(0.f, t * sc1[o] + sh1[o]);
    }
#pragma unroll
    for (int o4 = 0; o4 < 8; ++o4) {
      float r[4];
#pragma unroll
      for (int u = 0; u < 4; ++u) {
        int o = o4 * 4 + u;
        float a = 0.f;
#pragma unroll
        for (int c = 0; c < 32; ++c) a += h1[c] * w2s[o * 33 + c];
        r[u] = fmaxf(0.f, a * sc2[o] + sh2[o]);
      }
      *(unsigned*)&xh[row + o4 * 4] = (unsigned)f2bf(r[0]) | (((unsigned)f2bf(r[1])) << 16);
      *(unsigned*)&xh[row + o4 * 4 + 2] = (unsigned)f2bf(r[2]) | (((unsigned)f2bf(r[3])) << 16);
    }
    int jx = idx[bmk];
    const float4* xr = (const float4*)(xt + ((size_t)b * Np + jx) * 64);
#pragma unroll
    for (int c4 = 0; c4 < 16; ++c4) {
      float4 v = xr[c4];
      *(unsigned*)&xh[row + 32 + c4 * 4] = (unsigned)f2bf(v.x) | (((unsigned)f2bf(v.y)) << 16);
      *(unsigned*)&xh[row + 32 + c4 * 4 + 2] = (unsigned)f2bf(v.z) | (((unsigned)f2bf(v.w)) << 16);
    }
  }
  float Tr[16];
  {
    const float4* tg = (const float4*)(Tbuf + (size_t)(bm0 + bml) * 256 + j * 16);
#pragma unroll
    for (int w4 = 0; w4 < 4; ++w4) {
      float4 tv = tg[w4];
      Tr[w4 * 4 + 0] = tv.x; Tr[w4 * 4 + 1] = tv.y;
      Tr[w4 * 4 + 2] = tv.z; Tr[w4 * 4 + 3] = tv.w;
    }
  }
  __syncthreads();
#pragma unroll
  for (int c0 = 0; c0 < 96; c0 += 32) {
    float acc[32];
#pragma unroll
    for (int cc = 0; cc < 32; ++cc) acc[cc] = 0.f;
#pragma unroll
    for (int jj = 0; jj < 16; ++jj) {
      const unsigned* xr2 = (const unsigned*)&xh[(bml * 16 + jj) * 98 + c0];
      float t = Tr[jj];
#pragma unroll
      for (int cc = 0; cc < 16; ++cc) {
        unsigned uv = xr2[cc];
        acc[cc * 2] += t * bf2f_lo(uv);
        acc[cc * 2 + 1] += t * bf2f_hi(uv);
      }
    }
    unsigned* dst = (unsigned*)(x2 + (size_t)bmk * 96 + c0);
#pragma unroll
    for (int cc = 0; cc < 16; ++cc)
      dst[cc] = (unsigned)f2bf(acc[cc * 2]) | (((unsigned)f2bf(acc[cc * 2 + 1])) << 16);
  }
}

// ---------------- preout = x2(bf16) @ Wcrp^T + bc, MFMA 64x128, fused stats
__global__ __launch_bounds__(256) void preout_kernel(const unsigned short* __restrict__ x2,
                                                     const unsigned short* __restrict__ Wcrp,
                                                     const float* __restrict__ bc,
                                                     float* __restrict__ pout,
                                                     float* __restrict__ spout) {
  __shared__ unsigned short As[64 * 40], Bs[128 * 40];
  __shared__ float ls[256];
  int tid = threadIdx.x;
  ls[tid] = 0.f;
  int bm0 = blockIdx.x * 64;
  int wid = tid >> 6, lane = tid & 63;
  int wm = wid >> 1, wn = wid & 1;
  int mh = lane & 15, quad = lane >> 4;
  f32x4 acc[2][4];
#pragma unroll
  for (int a = 0; a < 2; ++a)
#pragma unroll
    for (int bq = 0; bq < 4; ++bq) acc[a][bq] = (f32x4){0.f, 0.f, 0.f, 0.f};
  int ar = tid >> 2, aseg = tid & 3;
  const unsigned short* Ag = x2 + (size_t)(bm0 + ar) * 1536 + aseg * 8;
  const unsigned short* Bg0 = Wcrp + (size_t)ar * 1536 + aseg * 8;
  const unsigned short* Bg1 = Wcrp + (size_t)(64 + ar) * 1536 + aseg * 8;
  int aoff = ar * 40 + aseg * 8;
  short8 a_pre = *(const short8*)Ag;
  short8 b_pre0 = *(const short8*)Bg0;
  short8 b_pre1 = *(const short8*)Bg1;
  for (int i0 = 0; i0 < 1536; i0 += 32) {
    __syncthreads();
    *(short8*)&As[aoff] = a_pre;
    *(short8*)&Bs[aoff] = b_pre0;
    *(short8*)&Bs[64 * 40 + aoff] = b_pre1;
    __syncthreads();
    if (i0 + 32 < 1536) {
      a_pre = *(const short8*)(Ag + i0 + 32);
      b_pre0 = *(const short8*)(Bg0 + i0 + 32);
      b_pre1 = *(const short8*)(Bg1 + i0 + 32);
    }
#pragma unroll
    for (int mt = 0; mt < 2; ++mt) {
      short8 af = *(const short8*)&As[(wm * 32 + mt * 16 + mh) * 40 + quad * 8];
#pragma unroll
      for (int nt = 0; nt < 4; ++nt) {
        short8 bf = *(const short8*)&Bs[(wn * 64 + nt * 16 + mh) * 40 + quad * 8];
        acc[mt][nt] = __builtin_amdgcn_mfma_f32_16x16x32_bf16(af, bf, acc[mt][nt], 0, 0, 0);
      }
    }
  }
#pragma unroll
  for (int mt = 0; mt < 2; ++mt)
#pragma unroll
    for (int nt = 0; nt < 4; ++nt) {
      int col = wn * 64 + nt * 16 + mh;
      float bvv = bc[col];
      float ps = 0.f, pq = 0.f;
#pragma unroll
      for (int r = 0; r < 4; ++r) {
        float val = acc[mt][nt][r] + bvv;
        pout[(size_t)(bm0 + wm * 32 + mt * 16 + quad * 4 + r) * 128 + col] = val;
        ps += val;
        pq += val * val;
      }
      atomicAdd(&ls[col], ps);
      atomicAdd(&ls[128 + col], pq);
    }
  __syncthreads();
  atomicAdd(&spout[tid], ls[tid]);
}

// ---------------- epilogue: blocks [0,192) copy q; [192,448) transpose+BN via LDS
__global__ __launch_bounds__(256) void final_kernel(const float* __restrict__ q,
                                                    const float* __restrict__ pout,
                                                    const float* __restrict__ scs,
                                                    const float* __restrict__ gc,
                                                    const float* __restrict__ bec,
                                                    float* __restrict__ dout) {
  __shared__ float ldsT[128 * 65];
  int blk = blockIdx.x;
  int tid = threadIdx.x;
  if (blk < 192) {
    int g = blk * 256 + tid;
    dout[g] = q[g];
    return;
  }
  int blk2 = blk - 192;
  int b = blk2 >> 5;
  int m0 = (blk2 & 31) * 64;
  int row = tid >> 2, seg = tid & 3;
  const float4* src = (const float4*)(pout + ((size_t)(b * Mq) + m0 + row) * 128 + seg * 32);
#pragma unroll
  for (int k4 = 0; k4 < 8; ++k4) {
    float4 v = src[k4];
    int o = seg * 32 + k4 * 4;
    ldsT[(o + 0) * 65 + row] = v.x;
    ldsT[(o + 1) * 65 + row] = v.y;
    ldsT[(o + 2) * 65 + row] = v.z;
    ldsT[(o + 3) * 65 + row] = v.w;
  }
  __syncthreads();
  int lane = tid & 63, wv = tid >> 6;
  float n = (float)BM;
  float* base = dout + (size_t)BM * 3 + (size_t)b * COUT * Mq + m0;
#pragma unroll
  for (int rep = 0; rep < 32; ++rep) {
    int o = wv * 32 + rep;
    float mean = scs[o] / n;
    float var = scs[128 + o] / n - mean * mean;
    float s = gc[o] * rsqrtf(var + EPS);
    float shv = bec[o] - mean * s;
    float v = ldsT[o * 65 + lane];
    base[(size_t)o * Mq + lane] = fmaxf(0.f, v * s + shv);
  }
}

extern "C" void kernel_launch(void* const* d_in, const int* in_sizes, int n_in, void* d_out,
                              int out_size, void* d_ws, size_t ws_size, hipStream_t stream) {
  const float* p = (const float*)d_in[0];
  const float* q = (const float*)d_in[1];
  const float* x = (const float*)d_in[2];
  const float* W1 = (const float*)d_in[3];
  const float* b1 = (const float*)d_in[4];
  const float* g1 = (const float*)d_in[5];
  const float* be1 = (const float*)d_in[6];
  const float* W2 = (const float*)d_in[7];
  const float* b2 = (const float*)d_in[8];
  const float* g2 = (const float*)d_in[9];
  const float* be2 = (const float*)d_in[10];
  const float* Ws1 = (const float*)d_in[11];
  const float* bs1 = (const float*)d_in[12];
  const float* gs1 = (const float*)d_in[13];
  const float* bes1 = (const float*)d_in[14];
  const float* Ws2 = (const float*)d_in[15];
  const float* bs2 = (const float*)d_in[16];
  const float* gs2 = (const float*)d_in[17];
  const float* bes2 = (const float*)d_in[18];
  const float* Ws3 = (const float*)d_in[19];
  const float* bs3 = (const float*)d_in[20];
  const float* Wc = (const float*)d_in[21];
  const float* bc = (const float*)d_in[22];
  const float* gc = (const float*)d_in[23];
  const float* bec = (const float*)d_in[24];
  float* dout = (float*)d_out;

  char* ws = (char*)d_ws;
  float* stats = (float*)ws;  // s1(9)@0, s2(64)@16, spt1@128, spt2@640, spout@1152
  size_t off = 8192;
  float4* pp4 = (float4*)(ws + off);  off += (size_t)Bb * Np * 16;      // 1 MB
  int* idxb = (int*)(ws + off);       off += (size_t)BMK * 4;           // 1 MB
  float* xt = (float*)(ws + off);     off += (size_t)Bb * Np * 64 * 4;  // 16 MB
  float* phat = (float*)(ws + off);   off += (size_t)BMK * 3 * 4;       // 3 MB
  float* pt1 = (float*)(ws + off);    off += (size_t)BM * 256 * 4;      // 16 MB
  float* pt2 = (float*)(ws + off);    off += (size_t)BM * 256 * 4;      // 16 MB
  float* Tb = (float*)(ws + off);     off += (size_t)BM * 256 * 4;      // 16 MB
  float* pout = (float*)(ws + off);   off += (size_t)BM * 128 * 4;      // 8 MB
  unsigned short* wcrp = (unsigned short*)(ws + off); off += (size_t)1536 * 128 * 2;
  unsigned short* x2 = (unsigned short*)(ws + off);   off += (size_t)BM * 1536 * 2;  // 48 MB
  int* hist = (int*)(ws + off);       off += (size_t)Bb * NC * 4;       // 128 KB
  int* cursor = (int*)(ws + off);     off += (size_t)Bb * NC * 4;       // 128 KB
  int* cellstart = (int*)(ws + off);  off += (size_t)Bb * (NC + 1) * 4; // ~128 KB
  float4* sp4 = (float4*)(ws + off);  off += (size_t)Bb * Np * 16;      // 1 MB
  int* sidx = (int*)(ws + off);       off += (size_t)Bb * Np * 4;       // 256 KB

  hipMemsetAsync(stats, 0, 8192, stream);
  hipMemsetAsync(hist, 0, (size_t)Bb * NC * 4, stream);
  hipLaunchKernelGGL(prep_kernel, dim3(2048), dim3(256), 0, stream, p, x, Wc, pp4, xt, wcrp, hist);
  hipLaunchKernelGGL(prefix_kernel, dim3(8), dim3(256), 0, stream, hist, cellstart, cursor);
  hipLaunchKernelGGL(scatter_kernel, dim3(256), dim3(256), 0, stream, pp4, cursor, sp4, sidx);
  hipLaunchKernelGGL(knn_kernel, dim3(2048), dim3(256), 0, stream, pp4, sp4, cellstart, q, idxb);
  hipLaunchKernelGGL(phat_stats_kernel, dim3(256), dim3(256), 0, stream, pp4, q, idxb, phat, stats);
  hipLaunchKernelGGL(stn1_kernel, dim3(512), dim3(256), 0, stream, phat, Ws1, bs1, pt1, stats + 128);
  hipLaunchKernelGGL(stats2_kernel, dim3(1024), dim3(256), 0, stream, phat, stats, W1, b1, g1, be1, W2, b2, stats + 16);
  hipLaunchKernelGGL(stn_mm_kernel, dim3(512), dim3(256), 0, stream, pt1, stats + 128, gs1, bes1, Ws2, bs2, pt2, stats + 640, 1);
  hipLaunchKernelGGL(stn_mm_kernel, dim3(512), dim3(256), 0, stream, pt2, stats + 640, gs2, bes2, Ws3, bs3, Tb, (float*)nullptr, 0);
  hipLaunchKernelGGL(xhat_x2_kernel, dim3(1024), dim3(256), 0, stream, phat, stats, stats + 16,
                     W1, b1, g1, be1, W2, b2, g2, be2, xt, idxb, Tb, x2);
  hipLaunchKernelGGL(preout_kernel, dim3(256), dim3(256), 0, stream, x2, wcrp, bc, pout, stats + 1152);
  hipLaunchKernelGGL(final_kernel, dim3(448), dim3(256), 0, stream, q, pout, stats + 1152, gc, bec, dout);
}